// Round 2
// baseline (7497.102 us; speedup 1.0000x reference)
//
#include <hip/hip_runtime.h>
#include <hip/hip_bf16.h>

// Problem constants (from reference)
#define NB 4
#define NL 256
#define ND 768
#define NH 12
#define NHD 64
#define NDFF 768
#define NSTEPS 6
#define NC 50257
#define NSLOTS 7
#define LNEPS 1e-5f

// ---------------------------------------------------------------------------
// Embedding: h_store[b][l][slot0][d] = emb[x[b][l]][d] + pos_emb[l][d]
// ---------------------------------------------------------------------------
__global__ __launch_bounds__(256) void k_embed(const int* __restrict__ x,
                                               const float* __restrict__ emb,
                                               const float* __restrict__ pos,
                                               float* __restrict__ h_store) {
  int idx = blockIdx.x * 256 + threadIdx.x;   // over NB*NL*ND
  int d = idx % ND;
  int bl = idx / ND;
  int l = bl % NL;
  int tok = x[bl];
  h_store[(size_t)bl * NSLOTS * ND + d] =
      emb[(size_t)tok * ND + d] + pos[(size_t)l * ND + d];
}

// h_store[b][l][t-1][d] += time_emb[t-1][d]   (persists across steps)
__global__ __launch_bounds__(256) void k_add_time(float* __restrict__ h_store,
                                                  const float* __restrict__ temb,
                                                  int t) {
  int idx = blockIdx.x * 256 + threadIdx.x;   // over NB*NL*ND
  int d = idx % ND;
  int bl = idx / ND;
  h_store[((size_t)bl * NSLOTS + (t - 1)) * ND + d] += temb[(size_t)(t - 1) * ND + d];
}

// x_cur[(b*L+l)*t + s][d] = h_store[b][l][s][d]
__global__ __launch_bounds__(256) void k_gather(const float* __restrict__ h_store,
                                                float* __restrict__ x_cur, int t) {
  int idx = blockIdx.x * 256 + threadIdx.x;   // over NB*NL*t*ND
  int d = idx % ND;
  int r = idx / ND;
  int s = r % t;
  int bl = r / t;
  x_cur[idx] = h_store[((size_t)bl * NSLOTS + s) * ND + d];
}

// h_store[b][l][t][d] = x_cur[(b*L+l)*t + (t-1)][d]
__global__ __launch_bounds__(256) void k_scatter(const float* __restrict__ x_cur,
                                                 float* __restrict__ h_store, int t) {
  int idx = blockIdx.x * 256 + threadIdx.x;   // over NB*NL*ND
  int d = idx % ND;
  int bl = idx / ND;
  h_store[((size_t)bl * NSLOTS + t) * ND + d] =
      x_cur[((size_t)bl * t + (t - 1)) * ND + d];
}

// ---------------------------------------------------------------------------
// fp32 GEMM: C[M][N] = A[M][K] (row stride lda) @ W[N][K]^T + bias[N]
// 64x64 tile, BK=16, 256 threads, 4x4 microtile. RELU=1 fuses relu.
// M must be a multiple of 64 (true for all call sites); N guarded.
// ---------------------------------------------------------------------------
template <int RELU>
__global__ __launch_bounds__(256) void k_gemm(const float* __restrict__ A, int lda,
                                              const float* __restrict__ W,
                                              const float* __restrict__ bias,
                                              float* __restrict__ Cmat,
                                              int M, int N, int K) {
  __shared__ float As[16][64];
  __shared__ float Ws[16][64];
  const int tid = threadIdx.x;
  const int m0 = blockIdx.y * 64;
  const int n0 = blockIdx.x * 64;
  const int lrow = tid >> 2;          // 0..63
  const int lk = (tid & 3) << 2;      // 0,4,8,12
  const int tm = tid >> 4;            // 0..15
  const int tn = tid & 15;            // 0..15
  const float* Ap = A + (size_t)(m0 + lrow) * lda + lk;
  const int wrow = n0 + lrow;
  const bool wv = wrow < N;
  const float* Wp = W + (size_t)wrow * K + lk;
  float acc[4][4] = {};
  for (int k0 = 0; k0 < K; k0 += 16) {
    float4 av = *(const float4*)(Ap + k0);
    float4 wvv = wv ? *(const float4*)(Wp + k0) : make_float4(0.f, 0.f, 0.f, 0.f);
    As[lk + 0][lrow] = av.x; As[lk + 1][lrow] = av.y;
    As[lk + 2][lrow] = av.z; As[lk + 3][lrow] = av.w;
    Ws[lk + 0][lrow] = wvv.x; Ws[lk + 1][lrow] = wvv.y;
    Ws[lk + 2][lrow] = wvv.z; Ws[lk + 3][lrow] = wvv.w;
    __syncthreads();
#pragma unroll
    for (int kk = 0; kk < 16; ++kk) {
      float4 a4 = *(const float4*)&As[kk][tm << 2];
      float4 w4 = *(const float4*)&Ws[kk][tn << 2];
      float a[4] = {a4.x, a4.y, a4.z, a4.w};
      float w[4] = {w4.x, w4.y, w4.z, w4.w};
#pragma unroll
      for (int i = 0; i < 4; ++i)
#pragma unroll
        for (int j = 0; j < 4; ++j) acc[i][j] = fmaf(a[i], w[j], acc[i][j]);
    }
    __syncthreads();
  }
#pragma unroll
  for (int i = 0; i < 4; ++i) {
    int m = m0 + (tm << 2) + i;
#pragma unroll
    for (int j = 0; j < 4; ++j) {
      int n = n0 + (tn << 2) + j;
      if (n < N) {
        float v = acc[i][j] + bias[n];
        if (RELU) v = fmaxf(v, 0.f);
        Cmat[(size_t)m * N + n] = v;
      }
    }
  }
}

// ---------------------------------------------------------------------------
// Sparse masked attention (thoughts mask): query q attends to keys k with
// k%t==0 (the 256 "line" keys k=j*t) plus its own block qb*t+s, s=1..t-1.
// One wave per (b,h,q) row, online softmax; lane = head dim for output,
// lane = key index for scores; p broadcast via shuffles (no LDS races).
// ---------------------------------------------------------------------------
__global__ __launch_bounds__(256) void k_attn(const float* __restrict__ qkv,
                                              const int* __restrict__ amask,
                                              float* __restrict__ O, int t) {
  const int S = NL * t;
  const int lane = threadIdx.x & 63;
  const int wave = threadIdx.x >> 6;
  const int flat = blockIdx.x * 4 + wave;   // b*H*S + h*S + q
  const int q = flat % S;
  const int bh = flat / S;
  const int h = bh % NH;
  const int b = bh / NH;
  const float* base = qkv + (size_t)b * S * (3 * ND);
  __shared__ float qs[4][64];
  qs[wave][lane] = base[(size_t)q * (3 * ND) + h * NHD + lane] * 0.125f;  // 1/sqrt(64)
  __syncthreads();  // qs read-only after this point
  const float* Kbase = base + ND + h * NHD;
  const float* Vbase = base + 2 * ND + h * NHD;
  const int qb = q / t;
  float m_run = -INFINITY, l_run = 0.f, o_acc = 0.f;
  const int NCH = NL / 64;  // 4 line-key chunks of 64
  for (int chunk = 0; chunk <= NCH; ++chunk) {
    int kidx;
    bool valid;
    if (chunk < NCH) {
      int j = chunk * 64 + lane;                 // key token j, key index j*t
      kidx = j * t;
      valid = (amask[b * NL + j] != 0);
    } else {
      int s = 1 + lane;                          // own-block keys (s=0 is a line key)
      kidx = qb * t + s;
      valid = (s < t) && (amask[b * NL + qb] != 0);
    }
    float sc = -INFINITY;
    if (valid) {
      const float4* Kr4 = (const float4*)(Kbase + (size_t)kidx * (3 * ND));
      const float4* qs4 = (const float4*)qs[wave];
      float acc = 0.f;
#pragma unroll
      for (int d4 = 0; d4 < 16; ++d4) {
        float4 kv = Kr4[d4];
        float4 qv = qs4[d4];
        acc = fmaf(qv.x, kv.x, acc);
        acc = fmaf(qv.y, kv.y, acc);
        acc = fmaf(qv.z, kv.z, acc);
        acc = fmaf(qv.w, kv.w, acc);
      }
      sc = acc;
    }
    float cm = sc;
#pragma unroll
    for (int off = 32; off; off >>= 1) cm = fmaxf(cm, __shfl_xor(cm, off));
    if (cm == -INFINITY) continue;  // only happens for t==1 block chunk (wave-uniform)
    float m_new = fmaxf(m_run, cm);
    float corr = __expf(m_run - m_new);  // m_run=-inf -> 0, correct
    m_run = m_new;                       // <-- fix: carry the running max forward
    float p = valid ? __expf(sc - m_new) : 0.f;
    float psum = p;
#pragma unroll
    for (int off = 32; off; off >>= 1) psum += __shfl_xor(psum, off);
    l_run = l_run * corr + psum;
    o_acc *= corr;
    if (chunk < NCH) {
      for (int j = 0; j < 64; ++j) {
        float pj = __shfl(p, j);
        if (pj > 0.f) {
          int kj = (chunk * 64 + j) * t;
          o_acc = fmaf(pj, Vbase[(size_t)kj * (3 * ND) + lane], o_acc);
        }
      }
    } else {
      for (int j = 0; j < t - 1; ++j) {
        float pj = __shfl(p, j);
        if (pj > 0.f) {
          int kj = qb * t + 1 + j;
          o_acc = fmaf(pj, Vbase[(size_t)kj * (3 * ND) + lane], o_acc);
        }
      }
    }
  }
  O[((size_t)b * S + q) * ND + h * NHD + lane] = o_acc / l_run;
}

// ---------------------------------------------------------------------------
// Fused residual-add + LayerNorm, in place into x. One wave per row (D=768).
// ---------------------------------------------------------------------------
__global__ __launch_bounds__(256) void k_add_ln(float* __restrict__ x,
                                                const float* __restrict__ r,
                                                const float* __restrict__ g,
                                                const float* __restrict__ bt) {
  const int lane = threadIdx.x & 63;
  const int wave = threadIdx.x >> 6;
  const int row = blockIdx.x * 4 + wave;
  float* xr = x + (size_t)row * ND;
  const float* rr = r + (size_t)row * ND;
  float v[12];
  float sum = 0.f, sq = 0.f;
#pragma unroll
  for (int i = 0; i < 12; ++i) {
    float tv = xr[lane + (i << 6)] + rr[lane + (i << 6)];
    v[i] = tv;
    sum += tv;
    sq = fmaf(tv, tv, sq);
  }
#pragma unroll
  for (int off = 32; off; off >>= 1) {
    sum += __shfl_xor(sum, off);
    sq += __shfl_xor(sq, off);
  }
  const float mean = sum * (1.f / ND);
  const float var = sq * (1.f / ND) - mean * mean;   // biased var, matches jnp.var
  const float rs = rsqrtf(var + LNEPS);
#pragma unroll
  for (int i = 0; i < 12; ++i) {
    int d = lane + (i << 6);
    xr[d] = (v[i] - mean) * rs * g[d] + bt[d];
  }
}

// ---------------------------------------------------------------------------
extern "C" void kernel_launch(void* const* d_in, const int* in_sizes, int n_in,
                              void* d_out, int out_size, void* d_ws, size_t ws_size,
                              hipStream_t stream) {
  const int* x = (const int*)d_in[0];
  const int* amask = (const int*)d_in[1];
  const float* emb = (const float*)d_in[2];
  const float* pos = (const float*)d_in[3];
  const float* temb = (const float*)d_in[4];
  const float* in_w = (const float*)d_in[5];
  const float* in_b = (const float*)d_in[6];
  const float* ao_w = (const float*)d_in[7];
  const float* ao_b = (const float*)d_in[8];
  const float* ln1g = (const float*)d_in[9];
  const float* ln1bv = (const float*)d_in[10];
  const float* w1 = (const float*)d_in[11];
  const float* b1 = (const float*)d_in[12];
  const float* w2 = (const float*)d_in[13];
  const float* b2 = (const float*)d_in[14];
  const float* ln2g = (const float*)d_in[15];
  const float* ln2bv = (const float*)d_in[16];
  const float* hw = (const float*)d_in[17];
  const float* hb = (const float*)d_in[18];
  float* outp = (float*)d_out;

  // Workspace layout (floats). Total = BLD*(7+6+18+6) = 29,097,984 f = 116.4 MB.
  float* ws = (float*)d_ws;
  const size_t BLD = (size_t)NB * NL * ND;       // 786432
  float* h_store = ws;                           // [B][L][7][D]
  float* x_cur   = h_store + BLD * NSLOTS;       // [B][S<=1536][D]
  float* qkvbuf  = x_cur + BLD * NSTEPS;         // [B][S][3D]
  float* attn_o  = qkvbuf + BLD * NSTEPS * 3;    // [B][S][D]
  float* proj    = qkvbuf;                       // reuse (qkv dead after attn)
  float* ff1     = qkvbuf + BLD * NSTEPS;
  float* ff2     = qkvbuf + BLD * NSTEPS * 2;

  k_embed<<<(NB * NL * ND) / 256, 256, 0, stream>>>(x, emb, pos, h_store);

  for (int t = 1; t <= NSTEPS; ++t) {
    const int S = NL * t;
    const int M = NB * S;   // multiple of 64
    k_add_time<<<(NB * NL * ND) / 256, 256, 0, stream>>>(h_store, temb, t);
    k_gather<<<(NB * NL * t * ND) / 256, 256, 0, stream>>>(h_store, x_cur, t);
    k_gemm<0><<<dim3((3 * ND) / 64, M / 64), 256, 0, stream>>>(
        x_cur, ND, in_w, in_b, qkvbuf, M, 3 * ND, ND);
    k_attn<<<(NB * NH * S) / 4, 256, 0, stream>>>(qkvbuf, amask, attn_o, t);
    k_gemm<0><<<dim3(ND / 64, M / 64), 256, 0, stream>>>(
        attn_o, ND, ao_w, ao_b, proj, M, ND, ND);
    k_add_ln<<<M / 4, 256, 0, stream>>>(x_cur, proj, ln1g, ln1bv);
    k_gemm<1><<<dim3(NDFF / 64, M / 64), 256, 0, stream>>>(
        x_cur, ND, w1, b1, ff1, M, NDFF, ND);
    k_gemm<0><<<dim3(ND / 64, M / 64), 256, 0, stream>>>(
        ff1, NDFF, w2, b2, ff2, M, ND, NDFF);
    k_add_ln<<<M / 4, 256, 0, stream>>>(x_cur, ff2, ln2g, ln2bv);
    k_scatter<<<(NB * NL * ND) / 256, 256, 0, stream>>>(x_cur, h_store, t);
  }

  // Head: last = h_store[:,:,6,:] (row stride 7*D), out[B*L][C]
  k_gemm<0><<<dim3((NC + 63) / 64, (NB * NL) / 64), 256, 0, stream>>>(
      h_store + (size_t)NSTEPS * ND, NSLOTS * ND, hw, hb, outp, NB * NL, NC, ND);
}